// Round 4
// baseline (197.285 us; speedup 1.0000x reference)
//
#include <hip/hip_runtime.h>
#include <hip/hip_bf16.h>
#include <stdint.h>

#define FEATURES 256
#define SYMBOLS  1024
#define NPIX     65536        // 16*64*64
#define M_TILE   128
#define THREADS  512          // 8 waves: wm = wave>>2 (64-row half), wn = wave&3 (32-col group)
#define A_BYTES  32768        // A image: 128 rows x 256 B fp8, persists whole kernel
#define TILE_BYTES 16384      // B tile: 128 syms x 128 feats fp8, pre-swizzled DMA image
#define SMEM_BYTES (A_BYTES + 2 * TILE_BYTES)   // 64 KB -> 2 blocks/CU = 16 waves/CU

typedef float f32x4 __attribute__((ext_vector_type(4)));
typedef long  lx2   __attribute__((ext_vector_type(2)));   // one b128 = two fp8 MFMA frags

// async global->LDS DMA, 16 B per lane; LDS dest = uniform base + lane*16
__device__ __forceinline__ void gld_lds16(const void* g, void* l) {
    __builtin_amdgcn_global_load_lds(
        (const __attribute__((address_space(1))) unsigned int*)g,
        (__attribute__((address_space(3))) unsigned int*)l, 16, 0, 0);
}

// pack 4 fp32 -> 4 fp8 e4m3 (OCP on gfx950), little-endian byte j = element j
__device__ __forceinline__ uint32_t pack_fp8x4(float a, float b, float c, float d) {
    uint32_t u = 0;
    u = __builtin_amdgcn_cvt_pk_fp8_f32(a, b, u, false);
    u = __builtin_amdgcn_cvt_pk_fp8_f32(c, d, u, true);
    return u;
}

// ---- prep: fp8 DMA-image codebook (scaled by 256 to stay in e4m3 normal range),
//      wnorm = ||w||^2 (fp32 exact), zero deviation slot.
// Tile tt = nc*2+kt: syms [nc*128,+128) x feats [kt*128,+128). Row n = 128 B = 8 x 16B
// blocks; logical block b = ksp*4+quad stored at phys b^(n&7); bytes j / 8+j =
// fp8(256*W[s][kt*128 + ksp*64 + quad*8 + j (+32)]).  -> ds_read_b128 yields frag pair.
__global__ __launch_bounds__(64) void vq_prep(const float* __restrict__ W,
                                              char* __restrict__ Wt,
                                              float* __restrict__ wnorm,
                                              float* __restrict__ devslot) {
    int s = blockIdx.x;
    int lane = threadIdx.x;
    int n  = s & 127;
    int nc = s >> 7;
    f32x4 v = ((const f32x4*)(W + (size_t)s * FEATURES))[lane];
    float ss = v[0]*v[0] + v[1]*v[1] + v[2]*v[2] + v[3]*v[3];
    #pragma unroll
    for (int off = 32; off > 0; off >>= 1) ss += __shfl_xor(ss, off);
    if (lane == 0) wnorm[s] = ss;
    if (s == 0 && lane == 0) *devslot = 0.f;

    if (lane < 16) {
        int kt = lane >> 3, b = lane & 7;
        int ksp = b >> 2, quad = b & 3;
        const float* src = W + (size_t)s * FEATURES + kt * 128 + ksp * 64 + quad * 8;
        uint32_t u0 = pack_fp8x4(256.f*src[0],  256.f*src[1],  256.f*src[2],  256.f*src[3]);
        uint32_t u1 = pack_fp8x4(256.f*src[4],  256.f*src[5],  256.f*src[6],  256.f*src[7]);
        uint32_t u2 = pack_fp8x4(256.f*src[32], 256.f*src[33], 256.f*src[34], 256.f*src[35]);
        uint32_t u3 = pack_fp8x4(256.f*src[36], 256.f*src[37], 256.f*src[38], 256.f*src[39]);
        uint4 blk = {u0, u1, u2, u3};
        *(uint4*)(Wt + (size_t)(nc * 2 + kt) * TILE_BYTES + n * 128 + ((b ^ (n & 7)) * 16)) = blk;
    }
}

// ---- main: fp8 fused GEMM-argmin + gather-out + deviation, 16 waves/CU ----
__global__ __launch_bounds__(THREADS, 4)      // cap 128 VGPR -> 4 waves/SIMD, no spill
void vq_main(
        const float*  __restrict__ x,
        const float*  __restrict__ W,
        const char*   __restrict__ Wt,
        const float*  __restrict__ wnorm,
        float*        __restrict__ out,
        float*        __restrict__ devslot) {
    extern __shared__ char smem[];
    const int t    = threadIdx.x;
    const int lane = t & 63;
    const int wave = t >> 6;             // 0..7
    const int quad = lane >> 4;
    const int l16  = lane & 15;
    const int wm   = wave >> 2;          // 0..1: 64-row half
    const int wn   = wave & 3;           // 0..3: 32-col group within each 128-col chunk
    const int m0   = blockIdx.x * M_TILE;
    const float scale = 1.25f / ((float)NPIX * (float)FEATURES);

    // ---- Stage A: x fp32 -> fp8 image (same block layout as B, 16 blocks/row) ----
    const f32x4* xblk = (const f32x4*)(x + (size_t)m0 * FEATURES);
    float ss = 0.f;
    #pragma unroll
    for (int i = 0; i < 16; ++i) {
        int idx = i * THREADS + t;       // 8192 float4
        int row = idx >> 6;              // wave-uniform
        int k4  = idx & 63;
        f32x4 v = xblk[idx];
        ss += v[0]*v[0] + v[1]*v[1] + v[2]*v[2] + v[3]*v[3];
        uint32_t u = pack_fp8x4(v[0], v[1], v[2], v[3]);
        int run = k4 >> 1;               // 8-feat run
        int ksp = run >> 3, half = (run >> 2) & 1, qb = run & 3;
        int blk = ksp * 4 + qb;          // logical block 0..15 (col ksp*64+half*32+qb*8)
        *(uint32_t*)(smem + row * 256 + ((blk ^ (row & 15)) * 16) + half * 8 + (k4 & 1) * 4) = u;
    }
    #pragma unroll
    for (int off = 32; off > 0; off >>= 1) ss += __shfl_xor(ss, off);
    if (lane == 0) atomicAdd(devslot, scale * ss);
    __syncthreads();

    // ---- af: feats 0..127 (ksp 0..1) persistent in regs; feats 128..255 stay in LDS ----
    lx2 af[4][2];
    #pragma unroll
    for (int mi = 0; mi < 4; ++mi) {
        int row = wm * 64 + mi * 16 + l16;
        #pragma unroll
        for (int ksp = 0; ksp < 2; ++ksp)
            af[mi][ksp] = *(const lx2*)(smem + row * 256 + (((ksp * 4 + quad) ^ (row & 15)) * 16));
    }

    char* const bs0 = smem + A_BYTES;
    char* const bs1 = smem + A_BYTES + TILE_BYTES;

    auto prefetch = [&](int tt) {        // lane-linear: tile tt is contiguous 16 KB
        const char* g = Wt + (size_t)tt * TILE_BYTES;
        char* buf = (tt & 1) ? bs1 : bs0;
        #pragma unroll
        for (int j = 0; j < 2; ++j) {
            int i = wave * 2 + j;        // 16 instrs x 1 KB
            gld_lds16(g + i * 1024 + lane * 16, buf + i * 1024);
        }
    };

    uint32_t best[16];
    #pragma unroll
    for (int j = 0; j < 16; ++j) best[j] = 0xFFFFFFFFu;

    prefetch(0);

    #pragma unroll 1
    for (int nc = 0; nc < 8; ++nc) {
        f32x4 acc[4][2] = {};
        #pragma unroll
        for (int kt = 0; kt < 2; ++kt) {
            const int tt = nc * 2 + kt;
            __syncthreads();             // drains vmcnt: buf[tt&1] ready
            if (tt < 15) prefetch(tt + 1);
            const char* buf = (tt & 1) ? bs1 : bs0;
            #pragma unroll
            for (int ksp = 0; ksp < 2; ++ksp) {
                lx2 bfr[2];
                #pragma unroll
                for (int ni = 0; ni < 2; ++ni) {
                    int n = wn * 32 + ni * 16 + l16;
                    bfr[ni] = *(const lx2*)(buf + n * 128 + (((ksp * 4 + quad) ^ (n & 7)) * 16));
                }
                lx2 a[4];
                #pragma unroll
                for (int mi = 0; mi < 4; ++mi) {
                    if (kt == 0) a[mi] = af[mi][ksp];
                    else {
                        int row = wm * 64 + mi * 16 + l16;
                        a[mi] = *(const lx2*)(smem + row * 256 +
                                ((((2 + ksp) * 4 + quad) ^ (row & 15)) * 16));
                    }
                }
                #pragma unroll
                for (int mi = 0; mi < 4; ++mi)
                    #pragma unroll
                    for (int ni = 0; ni < 2; ++ni) {
                        acc[mi][ni] = __builtin_amdgcn_mfma_f32_16x16x32_fp8_fp8(
                            a[mi][0], bfr[ni][0], acc[mi][ni], 0, 0, 0);
                        acc[mi][ni] = __builtin_amdgcn_mfma_f32_16x16x32_fp8_fp8(
                            a[mi][1], bfr[ni][1], acc[mi][ni], 0, 0, 0);
                    }
            }
        }
        // chunk epilogue: score = wnorm - (2/256)*acc ; packed-key running argmin
        #pragma unroll
        for (int ni = 0; ni < 2; ++ni) {
            int n = nc * 128 + wn * 32 + ni * 16 + l16;
            float wnv = wnorm[n];
            #pragma unroll
            for (int mi = 0; mi < 4; ++mi)
                #pragma unroll
                for (int r = 0; r < 4; ++r) {
                    float v2 = __builtin_fmaf(-0.0078125f, acc[mi][ni][r], wnv);
                    uint32_t u = __float_as_uint(v2);
                    u ^= (u & 0x80000000u) ? 0xFFFFFFFFu : 0x80000000u;  // monotone map
                    uint32_t key = (u & 0xFFFFFC00u) | (uint32_t)n;      // ties -> low idx
                    int j = mi * 4 + r;
                    if (key < best[j]) best[j] = key;
                }
        }
    }

    // merge over the 16 lanes of each quad (cols this lane held)
    #pragma unroll
    for (int j = 0; j < 16; ++j) {
        uint32_t v = best[j];
        #pragma unroll
        for (int off = 1; off < 16; off <<= 1) {
            uint32_t ov = (uint32_t)__shfl_xor((int)v, off);
            if (ov < v) v = ov;
        }
        best[j] = v;
    }

    // bs0 is dead (last tile lives in bs1; barrier at tt=15 passed) -> merge arrays there
    uint32_t* mslot = (uint32_t*)bs0;    // [4][128] per-wn candidates
    int*      codes = (int*)(bs0 + 2048);

    if (l16 == 0) {                      // quad-uniform data, one writer per quad
        #pragma unroll
        for (int j = 0; j < 16; ++j) {
            int mi = j >> 2, r = j & 3;
            int row = wm * 64 + mi * 16 + quad * 4 + r;
            mslot[wn * 128 + row] = best[j];
        }
    }
    __syncthreads();

    if (t < 128) {                       // merge 4 wn groups; deviation partial
        uint32_t s = mslot[t];
        #pragma unroll
        for (int g = 1; g < 4; ++g) {
            uint32_t o = mslot[g * 128 + t];
            if (o < s) s = o;
        }
        codes[t] = (int)(s & 1023u);
        uint32_t u = s & 0xFFFFFC00u;
        u = (u & 0x80000000u) ? (u & 0x7FFFFFFFu) : ~u;  // unmap monotone key
        float bv = __uint_as_float(u);   // = wnorm[code] - 2*best_dot (quantized)
        #pragma unroll
        for (int off = 32; off > 0; off >>= 1) bv += __shfl_xor(bv, off);
        if (lane == 0) atomicAdd(devslot, scale * bv);
    }
    __syncthreads();

    // ---- out = W[code] (exact fp32 gather from the original codebook) ----
    f32x4* oblk = (f32x4*)(out + (size_t)m0 * FEATURES);
    #pragma unroll
    for (int i = 0; i < 16; ++i) {
        int idx = i * THREADS + t;
        int row = idx >> 6;              // wave-uniform
        int k4  = idx & 63;
        int code = codes[row];
        oblk[idx] = ((const f32x4*)(W + (size_t)code * FEATURES))[k4];
    }
}

extern "C" void kernel_launch(void* const* d_in, const int* in_sizes, int n_in,
                              void* d_out, int out_size, void* d_ws, size_t ws_size,
                              hipStream_t stream) {
    const float* x = (const float*)d_in[0];
    const float* W = (const float*)d_in[1];
    float* out = (float*)d_out;

    char*  Wt    = (char*)d_ws;                                   // 256 KB fp8 tiles
    float* wnorm = (float*)((char*)d_ws + 16 * TILE_BYTES);       // 4 KB
    float* devslot = out + (size_t)NPIX * FEATURES;               // d_out tail

    hipFuncSetAttribute(reinterpret_cast<const void*>(vq_main),
                        hipFuncAttributeMaxDynamicSharedMemorySize, SMEM_BYTES);

    vq_prep<<<SYMBOLS, 64, 0, stream>>>(W, Wt, wnorm, devslot);
    vq_main<<<NPIX / M_TILE, THREADS, SMEM_BYTES, stream>>>(x, W, Wt, wnorm, out, devslot);
}

// Round 5
// 150.828 us; speedup vs baseline: 1.3080x; 1.3080x over previous
//
#include <hip/hip_runtime.h>
#include <hip/hip_bf16.h>
#include <stdint.h>

#define FEATURES 256
#define SYMBOLS  1024
#define NPIX     65536        // 16*64*64
#define M_TILE   128
#define THREADS  512          // 8 waves: wm = wave>>1 (32-row band), wn = wave&1 (64-col half)
#define A_BYTES  32768        // A image: 128 rows x 256 B fp8, swizzled, persistent
#define TILE_BYTES 16384      // B tile: 128 syms x 128 feats fp8, pre-swizzled DMA image
#define EXTRA_BYTES 2048      // mslot[256] + codes[128] + sspart[8]
#define SMEM_BYTES (A_BYTES + 2 * TILE_BYTES + EXTRA_BYTES)   // 66.5 KB -> 2 blocks/CU

typedef float f32x4  __attribute__((ext_vector_type(4)));
typedef float f32x16 __attribute__((ext_vector_type(16)));

// async global->LDS DMA, 16 B per lane; LDS dest = uniform base + lane*16
__device__ __forceinline__ void gld_lds16(const void* g, void* l) {
    __builtin_amdgcn_global_load_lds(
        (const __attribute__((address_space(1))) unsigned int*)g,
        (__attribute__((address_space(3))) unsigned int*)l, 16, 0, 0);
}

// pack 4 fp32 -> 4 fp8 e4m3 (OCP), byte j = element j   [validated R4: absmax 1.95e-3]
__device__ __forceinline__ uint32_t pack_fp8x4(float a, float b, float c, float d) {
    uint32_t u = 0;
    u = __builtin_amdgcn_cvt_pk_fp8_f32(a, b, u, false);
    u = __builtin_amdgcn_cvt_pk_fp8_f32(c, d, u, true);
    return u;
}

// ---- prep: fp8 DMA-image codebook (x256 scale keeps e4m3 normal), wnorm, dev=0 ----
// Tile tt=nc*2+kt: syms [nc*128,+128) x feats [kt*128,+128). Row n = 128 B = 16 8-B
// units; unit u (feats kt*128 + (u>>1)*16 + (u&1)*8 ..+8) stored at phys u^(n&15).
__global__ __launch_bounds__(64) void vq_prep(const float* __restrict__ W,
                                              char* __restrict__ Wt,
                                              float* __restrict__ wnorm,
                                              float* __restrict__ devslot) {
    int s = blockIdx.x;
    int lane = threadIdx.x;
    int n  = s & 127;
    int nc = s >> 7;
    f32x4 v = ((const f32x4*)(W + (size_t)s * FEATURES))[lane];
    float ss = v[0]*v[0] + v[1]*v[1] + v[2]*v[2] + v[3]*v[3];
    #pragma unroll
    for (int off = 32; off > 0; off >>= 1) ss += __shfl_xor(ss, off);
    if (lane == 0) wnorm[s] = ss;
    if (s == 0 && lane == 0) *devslot = 0.f;

    if (lane < 32) {
        int kt = lane >> 4;          // 0..1
        int u  = lane & 15;          // 8-B unit within the 128-B tile row
        const float* src = W + (size_t)s * FEATURES + kt * 128 + (u >> 1) * 16 + (u & 1) * 8;
        uint32_t a = pack_fp8x4(256.f*src[0], 256.f*src[1], 256.f*src[2], 256.f*src[3]);
        uint32_t b = pack_fp8x4(256.f*src[4], 256.f*src[5], 256.f*src[6], 256.f*src[7]);
        uint2 w2 = {a, b};
        *(uint2*)(Wt + (size_t)(nc * 2 + kt) * TILE_BYTES + n * 128 + ((u ^ (n & 15)) * 8)) = w2;
    }
}

// ---- main: 32x32x16 fp8, A-stationary (32 regs), DMA B, fused argmin ----
__global__ __launch_bounds__(THREADS)
__attribute__((amdgpu_waves_per_eu(4, 4)))   // pin 4 waves/EU: reg budget 128, no 64-reg spill mode
void vq_main(
        const float*  __restrict__ x,
        const float*  __restrict__ W,
        const char*   __restrict__ Wt,
        const float*  __restrict__ wnorm,
        float*        __restrict__ out,
        float*        __restrict__ devslot) {
    extern __shared__ char smem[];
    const int t    = threadIdx.x;
    const int lane = t & 63;
    const int wave = t >> 6;             // 0..7
    const int l32  = lane & 31;
    const int half = lane >> 5;          // k-half within a 16-K step
    const int wm   = wave >> 1;          // 0..3: 32-pixel-row band
    const int wn   = wave & 1;           // 0..1: 64-symbol-col half
    const int m0   = blockIdx.x * M_TILE;
    const float scale = 1.25f / ((float)NPIX * (float)FEATURES);

    char* const bs0 = smem + A_BYTES;
    char* const bs1 = smem + A_BYTES + TILE_BYTES;
    uint32_t* mslot = (uint32_t*)(smem + A_BYTES + 2 * TILE_BYTES);  // [2][128]
    int*      codes = (int*)(smem + A_BYTES + 2 * TILE_BYTES + 1024);
    float*    sspart = (float*)(smem + A_BYTES + 2 * TILE_BYTES + 1536);

    auto prefetch = [&](int tt) {        // lane-linear: tile tt is contiguous 16 KB
        const char* g = Wt + (size_t)tt * TILE_BYTES;
        char* buf = (tt & 1) ? bs1 : bs0;
        #pragma unroll
        for (int j = 0; j < 2; ++j) {
            int i = wave * 2 + j;        // 16 instrs x 1 KB
            gld_lds16(g + i * 1024 + lane * 16, buf + i * 1024);
        }
    };

    prefetch(0);                         // flies under the stage-A global loads

    // ---- Stage A: x fp32 -> fp8 image; row r = 256 B = 32 8-B units, phys = u^(r&31) ----
    const f32x4* xblk = (const f32x4*)(x + (size_t)m0 * FEATURES);
    float ss = 0.f;
    #pragma unroll
    for (int i = 0; i < 16; ++i) {
        int idx = i * THREADS + t;       // 8192 float4
        int row = idx >> 6;              // wave-uniform
        int k4  = idx & 63;
        f32x4 v = xblk[idx];
        ss += v[0]*v[0] + v[1]*v[1] + v[2]*v[2] + v[3]*v[3];
        uint32_t pk = pack_fp8x4(v[0], v[1], v[2], v[3]);
        int u = k4 >> 1;                 // unit 0..31
        *(uint32_t*)(smem + row * 256 + ((u ^ (row & 31)) * 8) + (k4 & 1) * 4) = pk;
    }
    #pragma unroll
    for (int off = 32; off > 0; off >>= 1) ss += __shfl_xor(ss, off);
    if (lane == 0) sspart[wave] = ss;
    __syncthreads();                     // A visible; DMA(0) drained

    // ---- A-stationary: af[s] = 8 fp8 for kstep s (k = s*16 + half*8 ..+8), 32 regs ----
    long af[16];
    {
        int r = wm * 32 + l32;           // pixel row (r&31 == l32)
        #pragma unroll
        for (int s = 0; s < 16; ++s)
            af[s] = *(const long*)(smem + r * 256 + (((s * 2 + half) ^ l32) * 8));
    }
    prefetch(1);

    uint32_t best[16];
    #pragma unroll
    for (int j = 0; j < 16; ++j) best[j] = 0xFFFFFFFFu;

    const int n0 = wn * 64 + l32;        // tile-local B rows for this lane
    const int n1 = wn * 64 + 32 + l32;

    #pragma unroll 1
    for (int nc = 0; nc < 8; ++nc) {
        f32x16 acc0 = {}, acc1 = {};
        #pragma unroll
        for (int kt = 0; kt < 2; ++kt) {
            const int tt = nc * 2 + kt;
            const char* buf = (tt & 1) ? bs1 : bs0;
            #pragma unroll
            for (int s2 = 0; s2 < 8; ++s2) {
                int u = s2 * 2 + half;
                long b0 = *(const long*)(buf + n0 * 128 + ((u ^ (n0 & 15)) * 8));
                long b1 = *(const long*)(buf + n1 * 128 + ((u ^ (n1 & 15)) * 8));
                acc0 = __builtin_amdgcn_mfma_f32_32x32x16_fp8_fp8(af[kt*8+s2], b0, acc0, 0, 0, 0);
                acc1 = __builtin_amdgcn_mfma_f32_32x32x16_fp8_fp8(af[kt*8+s2], b1, acc1, 0, 0, 0);
            }
            if (tt < 15) {
                __syncthreads();                 // readers done + prefetch(tt+1) drained
                if (tt + 2 <= 15) prefetch(tt + 2);
            }
        }
        // epilogue: score = wnorm - (2/256)*acc; packed-key running argmin
        int nb0 = nc * 128 + wn * 64 + l32;
        float w0 = wnorm[nb0], w1 = wnorm[nb0 + 32];
        #pragma unroll
        for (int r = 0; r < 16; ++r) {
            float v0 = __builtin_fmaf(-0.0078125f, acc0[r], w0);
            float v1 = __builtin_fmaf(-0.0078125f, acc1[r], w1);
            uint32_t u0 = __float_as_uint(v0);
            u0 ^= (u0 & 0x80000000u) ? 0xFFFFFFFFu : 0x80000000u;
            uint32_t k0 = (u0 & 0xFFFFFC00u) | (uint32_t)nb0;
            uint32_t u1 = __float_as_uint(v1);
            u1 ^= (u1 & 0x80000000u) ? 0xFFFFFFFFu : 0x80000000u;
            uint32_t k1 = (u1 & 0xFFFFFC00u) | (uint32_t)(nb0 + 32);
            if (k0 < best[r]) best[r] = k0;
            if (k1 < best[r]) best[r] = k1;
        }
    }

    // cross-lane merge within each 32-lane group (cols of this lane's rows)
    #pragma unroll
    for (int r = 0; r < 16; ++r) {
        uint32_t v = best[r];
        #pragma unroll
        for (int off = 1; off < 32; off <<= 1) {
            uint32_t ov = (uint32_t)__shfl_xor((int)v, off);
            if (ov < v) v = ov;
        }
        best[r] = v;
    }
    if (l32 == 0) {                      // lanes 0 and 32: rows differ by 4*half
        #pragma unroll
        for (int r = 0; r < 16; ++r) {
            int row = wm * 32 + (r & 3) + 8 * (r >> 2) + 4 * half;
            mslot[wn * 128 + row] = best[r];
        }
    }
    __syncthreads();

    if (t < 128) {                       // merge wn halves; deviation partials
        uint32_t s0 = mslot[t], s1 = mslot[128 + t];
        uint32_t s = (s1 < s0) ? s1 : s0;
        codes[t] = (int)(s & 1023u);
        uint32_t u = s & 0xFFFFFC00u;
        u = (u & 0x80000000u) ? (u & 0x7FFFFFFFu) : ~u;   // unmap monotone key
        float bv = __uint_as_float(u);   // = wnorm[code] - 2*best_dot (quantized)
        #pragma unroll
        for (int off = 32; off > 0; off >>= 1) bv += __shfl_xor(bv, off);
        if (lane == 0) atomicAdd(devslot, scale * bv);
        if (t == 0) {
            float sst = 0.f;
            #pragma unroll
            for (int w = 0; w < 8; ++w) sst += sspart[w];
            atomicAdd(devslot, scale * sst);
        }
    }
    __syncthreads();

    // ---- out = W[code] (exact fp32 gather from the original codebook) ----
    f32x4* oblk = (f32x4*)(out + (size_t)m0 * FEATURES);
    #pragma unroll
    for (int i = 0; i < 16; ++i) {
        int idx = i * THREADS + t;
        int row = idx >> 6;              // wave-uniform
        int k4  = idx & 63;
        int code = codes[row];
        oblk[idx] = ((const f32x4*)(W + (size_t)code * FEATURES))[k4];
    }
}

extern "C" void kernel_launch(void* const* d_in, const int* in_sizes, int n_in,
                              void* d_out, int out_size, void* d_ws, size_t ws_size,
                              hipStream_t stream) {
    const float* x = (const float*)d_in[0];
    const float* W = (const float*)d_in[1];
    float* out = (float*)d_out;

    char*  Wt    = (char*)d_ws;                                   // 256 KB fp8 tiles
    float* wnorm = (float*)((char*)d_ws + 16 * TILE_BYTES);       // 4 KB
    float* devslot = out + (size_t)NPIX * FEATURES;               // d_out tail

    hipFuncSetAttribute(reinterpret_cast<const void*>(vq_main),
                        hipFuncAttributeMaxDynamicSharedMemorySize, SMEM_BYTES);

    vq_prep<<<SYMBOLS, 64, 0, stream>>>(W, Wt, wnorm, devslot);
    vq_main<<<NPIX / M_TILE, THREADS, SMEM_BYTES, stream>>>(x, W, Wt, wnorm, out, devslot);
}